// Round 4
// baseline (21251.471 us; speedup 1.0000x reference)
//
#include <hip/hip_runtime.h>

#define S_LEN 131072
#define NIN   100
#define NH    40
#define TANH_SCALE 2.8853900817779268f   // 2*log2(e), folded into Wh/xproj

// ---------------------------------------------------------------------------
// Cross-row replicate: from H (lane l holds h[l]) produce 4 vectors, each one
// 16-wide column-group replicated across all rows. Slot->group mapping is
// direction-dependent -> MEASURED in k_scan's preamble (the permutation is
// provably slot = group XOR g0), so swap direction/return order never matter.
// ---------------------------------------------------------------------------
#if defined(__has_builtin)
#if __has_builtin(__builtin_amdgcn_permlane32_swap) && __has_builtin(__builtin_amdgcn_permlane16_swap)
#define HAS_PLSWAP 1
#endif
#endif
#ifndef HAS_PLSWAP
#define HAS_PLSWAP 0
#endif

#if HAS_PLSWAP
typedef unsigned int v2u __attribute__((ext_vector_type(2)));

__device__ __forceinline__ void plswap32(float& a, float& b) {
    v2u r = __builtin_amdgcn_permlane32_swap((unsigned)__float_as_int(a),
                                             (unsigned)__float_as_int(b), false, false);
    a = __int_as_float((int)r[0]);
    b = __int_as_float((int)r[1]);
}
__device__ __forceinline__ void plswap16(float& a, float& b) {
    v2u r = __builtin_amdgcn_permlane16_swap((unsigned)__float_as_int(a),
                                             (unsigned)__float_as_int(b), false, false);
    a = __int_as_float((int)r[0]);
    b = __int_as_float((int)r[1]);
}
#endif

__device__ __forceinline__ void replicate4(float H, volatile float* rl, int lane,
                                           float& v00, float& v01, float& v10, float& v11) {
#if HAS_PLSWAP
    (void)rl; (void)lane;
    float A = H, B = H;
    plswap32(A, B);                       // halves exchanged/replicated
    v00 = A; v01 = A; plswap16(v00, v01); // row-replicated pair from A
    v10 = B; v11 = B; plswap16(v10, v11); // row-replicated pair from B
#else
    // guaranteed-correct fallback: single-wave LDS broadcast (slower)
    rl[lane] = H;
    int l15 = lane & 15;
    v00 = rl[l15];
    v01 = rl[16 + l15];
    v10 = rl[32 + l15];
    v11 = rl[48 + l15];
#endif
}

// ---------------------------------------------------------------------------
// phase 1: xsT[i][t] = (s[t]·Wx[i] + Wx_b[i] + Wh_b[i]) * TANH_SCALE
// rows 40..63 zero-padded. Transposed [64][S] so the scan loads float4s.
// Each s-tile loaded ONCE (block computes all 64 rows).
// ---------------------------------------------------------------------------
__global__ __launch_bounds__(256) void k_xproj(const float* __restrict__ s,
                                               const float* __restrict__ Wx,
                                               const float* __restrict__ Wxb,
                                               const float* __restrict__ Whb,
                                               float* __restrict__ xsT) {
    __shared__ float sm[64][NIN + 1];
    int tx = threadIdx.x, ty = threadIdx.y;
    int tid = ty * 64 + tx;
    size_t t0 = (size_t)blockIdx.x * 64;
    for (int e = tid; e < 64 * NIN; e += 256) {
        int r = e / NIN, c = e - r * NIN;
        sm[r][c] = s[(t0 + r) * NIN + c];
    }
    __syncthreads();
    size_t tcol = t0 + tx;
    for (int ig = 0; ig < 16; ++ig) {
        int i = ig * 4 + ty;                      // wave-uniform row index
        float res = 0.0f;
        if (i < NH) {
            float acc = Wxb[i] + Whb[i];
            const float* wr = Wx + i * NIN;
#pragma unroll
            for (int k = 0; k < NIN; ++k) acc = fmaf(sm[tx][k], wr[k], acc);
            res = acc * TANH_SCALE;
        }
        xsT[(size_t)i * S_LEN + tcol] = res;
    }
}

// ---------------------------------------------------------------------------
// phase 2: the serial scan. One wave; lane l owns output row l.
// 40x40 matvec = col-groups x rotations of v_fmac_f32_dpp row_ror:K.
// Group 2 (cols 32..39, 8 real cols): FAST path uses an 8-periodic R2
// (update_dpp row_ror:8 + cndmask) so only rotations K=0..7 are needed.
// ---------------------------------------------------------------------------
#define FMAC_ROR(ACC, RS, WS, K)                                                        \
    asm volatile("v_fmac_f32_dpp %0, %1, %2 row_ror:" #K " row_mask:0xf bank_mask:0xf"  \
                 : "+v"(ACC) : "v"(RS), "v"(WS))

template <int V, bool FAST>
__device__ __forceinline__ void step_one(float xp, float& H, const float (&w)[3][16],
                                         bool sel, volatile float* rl, int lane) {
    float r00, r01, r10, r11;
    replicate4(H, rl, lane, r00, r01, r10, r11);
    // measured slot -> col-group mapping (permutation is slot = group XOR g0)
    float R0  = (V == 0) ? r00 : (V == 1) ? r01 : (V == 2) ? r10 : r11;
    float R1  = (V == 0) ? r01 : (V == 1) ? r00 : (V == 2) ? r11 : r10;
    float R2p = (V == 0) ? r10 : (V == 1) ? r11 : (V == 2) ? r00 : r01;
    float R2;
    if constexpr (FAST) {
        // make R2 8-periodic: R2[l] = h[32 + (l&7)]. sel (loop-invariant bool,
        // probed in preamble) picks rot vs plain per lane-half. Builtins ->
        // compiler inserts any required DPP wait-states itself.
        int roti = __builtin_amdgcn_update_dpp(0, __float_as_int(R2p), 0x128, 0xF, 0xF, false);
        R2 = sel ? __int_as_float(roti) : R2p;
    } else {
        R2 = R2p;
    }
    // k=0 terms as VOLATILE asm: guarantees >=3 non-DPP instructions between the
    // cross-lane writes of R0/R1/R2 and the first asm DPP read (the hazard
    // recognizer cannot see that our inline asm is DPP).
    float a0 = xp, a1, a2;
    asm volatile("v_fmac_f32 %0, %1, %2" : "+v"(a0) : "v"(R0), "v"(w[0][0]));
    asm volatile("v_mul_f32 %0, %1, %2" : "=v"(a1) : "v"(R1), "v"(w[1][0]));
    asm volatile("v_mul_f32 %0, %1, %2" : "=v"(a2) : "v"(R2), "v"(w[2][0]));
#define KSTEP(K)                                                        \
    {                                                                   \
        FMAC_ROR(a0, R0, w[0][K], K);                                   \
        FMAC_ROR(a1, R1, w[1][K], K);                                   \
        if constexpr (!FAST || (K) <= 7) { FMAC_ROR(a2, R2, w[2][K], K); } \
    }
    KSTEP(1) KSTEP(2) KSTEP(3) KSTEP(4) KSTEP(5) KSTEP(6) KSTEP(7)
    KSTEP(8) KSTEP(9) KSTEP(10) KSTEP(11) KSTEP(12) KSTEP(13) KSTEP(14) KSTEP(15)
#undef KSTEP
    float aa = (a0 + a1) + a2;                    // aa = z * 2*log2(e)  (pre-scaled)
    float ex = __builtin_amdgcn_exp2f(aa);        // e^{2z}
    H = fmaf(-2.0f, __builtin_amdgcn_rcpf(ex + 1.0f), 1.0f);   // tanh(z)
}

template <int V, bool FAST>
__device__ void scan_run(float H, const float (&w)[3][16], bool sel,
                         const float* __restrict__ xsT, float* __restrict__ hT,
                         int lane, float* __restrict__ out, volatile float* rl) {
    const float4* xr = (const float4*)(xsT + (size_t)lane * S_LEN);
    float4* hw4 = (float4*)(hT + (size_t)lane * S_LEN);
    float4 cA = xr[0], cB = xr[1];
    float4 hb;
    for (int t = 0; t < S_LEN; t += 16) {
        int q = t >> 2;
        float4 nA = xr[q + 2], nB = xr[q + 3];    // prefetch steps t+8..t+15
        step_one<V, FAST>(cA.x, H, w, sel, rl, lane); hb.x = H;
        step_one<V, FAST>(cA.y, H, w, sel, rl, lane); hb.y = H;
        step_one<V, FAST>(cA.z, H, w, sel, rl, lane); hb.z = H;
        step_one<V, FAST>(cA.w, H, w, sel, rl, lane); hb.w = H;
        hw4[q] = hb;
        step_one<V, FAST>(cB.x, H, w, sel, rl, lane); hb.x = H;
        step_one<V, FAST>(cB.y, H, w, sel, rl, lane); hb.y = H;
        step_one<V, FAST>(cB.z, H, w, sel, rl, lane); hb.z = H;
        step_one<V, FAST>(cB.w, H, w, sel, rl, lane); hb.w = H;
        hw4[q + 1] = hb;
        cA = xr[q + 4];                            // prefetch next iter t+16..t+23
        cB = xr[q + 5];                            // (last-iter 16B overrun stays inside d_out)
        step_one<V, FAST>(nA.x, H, w, sel, rl, lane); hb.x = H;
        step_one<V, FAST>(nA.y, H, w, sel, rl, lane); hb.y = H;
        step_one<V, FAST>(nA.z, H, w, sel, rl, lane); hb.z = H;
        step_one<V, FAST>(nA.w, H, w, sel, rl, lane); hb.w = H;
        hw4[q + 2] = hb;
        step_one<V, FAST>(nB.x, H, w, sel, rl, lane); hb.x = H;
        step_one<V, FAST>(nB.y, H, w, sel, rl, lane); hb.y = H;
        step_one<V, FAST>(nB.z, H, w, sel, rl, lane); hb.z = H;
        step_one<V, FAST>(nB.w, H, w, sel, rl, lane); hb.w = H;
        hw4[q + 3] = hb;
    }
    if (lane < NH) out[lane] = H;                  // h_final
}

__global__ __launch_bounds__(64) void k_scan(const float* __restrict__ xsT,
                                             float* __restrict__ hT,
                                             const float* __restrict__ Whw,
                                             const float* __restrict__ h0,
                                             float* __restrict__ out) {
    __shared__ float rl[64];
    int lane = threadIdx.x;

    // ---- preamble: measure slot->group mapping of replicate4 on this HW ----
    float v00, v01, v10, v11;
    replicate4(__int_as_float(lane), rl, lane, v00, v01, v10, v11);
    int J0 = __float_as_int(v00), J1 = __float_as_int(v01);
    int J2 = __float_as_int(v10), J3 = __float_as_int(v11);
    int g0 = __builtin_amdgcn_readfirstlane(J0) >> 4;   // J = 16*g + (lane&15)
    int g1 = __builtin_amdgcn_readfirstlane(J1) >> 4;
    int g2 = __builtin_amdgcn_readfirstlane(J2) >> 4;
    int g3 = __builtin_amdgcn_readfirstlane(J3) >> 4;

    // ---- probe the FAST group-2 transform on the index vector ----
    int Jg2 = (g0 == 2) ? J0 : (g1 == 2) ? J1 : (g2 == 2) ? J2 : J3;
    int rot2 = __builtin_amdgcn_update_dpp(0, Jg2, 0x128, 0xF, 0xF, false); // row_ror:8
    int needed = 32 + (lane & 7);
    bool selrot = (rot2 == needed);
    bool okfast = __all(selrot || (Jg2 == needed)) != 0;   // every lane can build 32+(l&7)

    // ---- build pre-skewed, pre-scaled Wh in registers ----
    float w[3][16];
#pragma unroll
    for (int c = 0; c < 3; ++c) {
        int Jc = (g0 == c) ? J0 : (g1 == c) ? J1 : (g2 == c) ? J2 : J3;
        int base = (c == 2 && okfast) ? needed : Jc;   // FAST: rotate the final 8-periodic index
        {
            int col = base;
            w[c][0] = (lane < NH && col < NH) ? Whw[lane * NH + col] * TANH_SCALE : 0.0f;
        }
#define WK(K)                                                                       \
    {                                                                               \
        int col = __builtin_amdgcn_update_dpp(0, base, 0x120 + K, 0xF, 0xF, false); \
        w[c][K] = (lane < NH && col < NH) ? Whw[lane * NH + col] * TANH_SCALE : 0.0f; \
    }
        WK(1) WK(2) WK(3) WK(4) WK(5) WK(6) WK(7) WK(8)
        WK(9) WK(10) WK(11) WK(12) WK(13) WK(14) WK(15)
#undef WK
    }

    float H = (lane < NH) ? h0[lane] : 0.0f;
    if (okfast) {
        switch (g0) {
            case 0:  scan_run<0, true>(H, w, selrot, xsT, hT, lane, out, rl); break;
            case 1:  scan_run<1, true>(H, w, selrot, xsT, hT, lane, out, rl); break;
            case 2:  scan_run<2, true>(H, w, selrot, xsT, hT, lane, out, rl); break;
            default: scan_run<3, true>(H, w, selrot, xsT, hT, lane, out, rl); break;
        }
    } else {
        switch (g0) {
            case 0:  scan_run<0, false>(H, w, selrot, xsT, hT, lane, out, rl); break;
            case 1:  scan_run<1, false>(H, w, selrot, xsT, hT, lane, out, rl); break;
            case 2:  scan_run<2, false>(H, w, selrot, xsT, hT, lane, out, rl); break;
            default: scan_run<3, false>(H, w, selrot, xsT, hT, lane, out, rl); break;
        }
    }
}

// ---------------------------------------------------------------------------
// phase 3: ys[t] = softmax(h_{t+1}·Wy^T + Wy_b). One wave per timestep;
// lane v handles vocab entries v and v+64.
// ---------------------------------------------------------------------------
__global__ __launch_bounds__(256) void k_out(const float* __restrict__ hT,
                                             const float* __restrict__ Wy,
                                             const float* __restrict__ Wyb,
                                             float* __restrict__ out) {
    int lane = threadIdx.x & 63;
    int wv = threadIdx.x >> 6;
    int t = __builtin_amdgcn_readfirstlane(blockIdx.x * 4 + wv);
    const float* hp = hT + t;
    float hv[NH];
#pragma unroll
    for (int j = 0; j < NH; ++j) hv[j] = hp[(size_t)j * S_LEN];  // wave-uniform loads
    int v = lane;
    const float* wr0 = Wy + v * NH;
    float z0 = Wyb[v];
#pragma unroll
    for (int j = 0; j < NH; ++j) z0 = fmaf(hv[j], wr0[j], z0);
    bool has2 = (v < NIN - 64);
    int v2 = v + 64;
    float z1 = -1e30f;
    if (has2) {
        const float* wr1 = Wy + v2 * NH;
        float acc = Wyb[v2];
#pragma unroll
        for (int j = 0; j < NH; ++j) acc = fmaf(hv[j], wr1[j], acc);
        z1 = acc;
    }
    float mx = fmaxf(z0, z1);
#pragma unroll
    for (int o = 32; o; o >>= 1) mx = fmaxf(mx, __shfl_xor(mx, o, 64));
    const float LOG2E = 1.4426950408889634f;
    float e0 = __builtin_amdgcn_exp2f((z0 - mx) * LOG2E);
    float e1 = 0.0f;
    if (has2) e1 = __builtin_amdgcn_exp2f((z1 - mx) * LOG2E);
    float sum = e0 + e1;
#pragma unroll
    for (int o = 32; o; o >>= 1) sum += __shfl_xor(sum, o, 64);
    float r = __builtin_amdgcn_rcpf(sum);
    r = r * (2.0f - sum * r);                     // Newton step -> ~exact division
    float* yrow = out + NH + (size_t)t * NIN;
    yrow[v] = e0 * r;
    if (has2) yrow[v2] = e1 * r;
}

// ---------------------------------------------------------------------------
extern "C" void kernel_launch(void* const* d_in, const int* in_sizes, int n_in,
                              void* d_out, int out_size, void* d_ws, size_t ws_size,
                              hipStream_t stream) {
    const float* s   = (const float*)d_in[0];
    const float* h0  = (const float*)d_in[1];
    const float* Wxw = (const float*)d_in[2];
    const float* Wxb = (const float*)d_in[3];
    const float* Whw = (const float*)d_in[4];
    const float* Whb = (const float*)d_in[5];
    const float* Wyw = (const float*)d_in[6];
    const float* Wyb = (const float*)d_in[7];
    float* out = (float*)d_out;

    // xsT [64][S] lives inside the ys region of d_out (fully overwritten later
    // by k_out, which never reads xsT). 16B-aligned (offset 160B).
    float* xsT = out + NH;
    // hT [64][S] (per-lane rows) in workspace: 33.55 MB.
    float* hT = (float*)d_ws;

    k_xproj<<<dim3(S_LEN / 64), dim3(64, 4), 0, stream>>>(s, Wxw, Wxb, Whb, xsT);
    k_scan<<<1, 64, 0, stream>>>(xsT, hT, Whw, h0, out);
    k_out<<<S_LEN / 4, 256, 0, stream>>>(hT, Wyw, Wyb, out);
}